// Round 6
// baseline (287.211 us; speedup 1.0000x reference)
//
#include <hip/hip_runtime.h>

// QAttentionLayer: out[..., i] = prod_{j<=i} cos(x_j)*cos(w_j), rows of 10 fp32.
// App traffic 335.5 MB; HBM-side ~244 MB (L3 absorbs half the fetch) -> floor ~40-53 us.
//
// Ledger (bench = ~186.5 us harness fills + kernel):
//   R0 (scalar LDS + conflicts + barriers)        kernel ~97 us
//   R2 (b128 LDS + gll DMA + barriers)            kernel ~96 us
//   R5 (wave-autonomous, zero barriers)           kernel ~95 us
//   R4 (persistent+pipelined BUT 16 waves/CU, block barriers, nt): 101 us
//   R3b (no LDS, 80B-stride stores): WRITE 3.4x -> LDS store transpose mandatory.
// R4 profile: HBM-side only 2.6 TB/s at 95 us -> NOT memory-bound; per-CU math
// (one 10KiB tile per 1781 cy vs ~1500 cy serial chain) says one-shot waves +
// dispatch churn leave slots idle: concurrency-starved.
//
// R6: PERSISTENT wave-autonomous pipeline. 2048 blocks (8/CU, 20 KiB LDS,
// <=64 VGPR), each wave grid-strides over 4 tiles, 1-deep prefetch:
//   [tile's gll landed] -> ds_read rowpair -> compute -> ds_write -> lgkm(0)
//   -> ds_read linear -> lgkm(0) [buffer fully consumed]
//   -> STAGE(next) into SAME buffer -> sched_barrier -> stores
//   -> vmcnt(5)  (gll issued BEFORE stores -> older; <=5 outstanding == the 5
//      stores -> gll landed; store retirement never waited on; no vmcnt(0) in loop)
// No barriers, no nt stores, 32 waves/CU.
//
// Predicted: kernel 95 -> ~55-65 us, bench -> ~242-252. If unchanged,
// persistence exonerated -> probe direct-register loads next.

#define BLOCK 256
#define WAVES 4
#define NQ 10
#define WQ 320                    // f32x4 per wave-tile = 5 KiB = 128 rows
#define ROWS_PER_TILE 128
#define MAX_BLOCKS 2048           // 8 blocks/CU * 256 CU

typedef float f32x4 __attribute__((ext_vector_type(4)));

__global__ __launch_bounds__(BLOCK, 8) void qcircuit_kernel(
    const float* __restrict__ x,
    const float* __restrict__ w,
    float* __restrict__ out,
    long long n_rows,
    long long nfull)              // number of full 128-row wave-tiles
{
    __shared__ f32x4 buf[WAVES * WQ];   // 20 KiB -> 8 blocks/CU

    const int tid  = threadIdx.x;
    const int wid  = tid >> 6;
    const int lane = tid & 63;
    f32x4* wbuf = buf + wid * WQ;

    const f32x4* __restrict__ gin  = (const f32x4*)x;
    f32x4* __restrict__       gout = (f32x4*)out;

    float cw[NQ];
    #pragma unroll
    for (int j = 0; j < NQ; ++j) cw[j] = __cosf(w[j]);

#define STAGE(t)                                                               \
    _Pragma("unroll")                                                          \
    for (int p = 0; p < 5; ++p) {                                              \
        __builtin_amdgcn_global_load_lds(                                      \
            (const __attribute__((address_space(1))) void*)                    \
                (gin + (t) * WQ + p * 64 + lane),                              \
            (__attribute__((address_space(3))) void*)(wbuf + p * 64 + lane),   \
            16, 0, 0);                                                         \
    }

    const long long nslots = (long long)gridDim.x * WAVES;
    const long long w0 = (long long)blockIdx.x * WAVES + wid;

    if (w0 < nfull) {
        STAGE(w0);
        asm volatile("s_waitcnt vmcnt(0)" ::: "memory");   // prologue only
    }

    for (long long wt = w0; wt < nfull; wt += nslots) {
        const long long base = wt * WQ;
        const long long nx   = wt + nslots;

        // ---- compute: lane owns row-pair 'lane' (5 f32x4, in-place) ----
        float v[20];                        // static indexing -> VGPRs
        f32x4* vr = (f32x4*)v;
        #pragma unroll
        for (int k = 0; k < 5; ++k) vr[k] = wbuf[lane * 5 + k];

        float pr = 1.0f;
        #pragma unroll
        for (int j = 0; j < NQ; ++j) { pr *= __cosf(v[j]) * cw[j]; v[j] = pr; }
        pr = 1.0f;
        #pragma unroll
        for (int j = 0; j < NQ; ++j) { pr *= __cosf(v[NQ + j]) * cw[j]; v[NQ + j] = pr; }

        #pragma unroll
        for (int k = 0; k < 5; ++k) wbuf[lane * 5 + k] = vr[k];
        asm volatile("s_waitcnt lgkmcnt(0)" ::: "memory"); // writes visible to own reads

        // ---- linear re-read into registers; buffer then fully consumed ----
        f32x4 sv[5];
        #pragma unroll
        for (int p = 0; p < 5; ++p) sv[p] = wbuf[p * 64 + lane];
        asm volatile("s_waitcnt lgkmcnt(0)" ::: "memory"); // sv in VGPRs, wbuf dead

        // ---- prefetch next tile into the SAME buffer (writes land later) ----
        if (nx < nfull) { STAGE(nx); }
        __builtin_amdgcn_sched_barrier(0);  // pin: gll issued BEFORE the stores

        // ---- coalesced stores (full 64B lines per 4 lanes) ----
        #pragma unroll
        for (int p = 0; p < 5; ++p) gout[base + p * 64 + lane] = sv[p];

        // gll (older) done when <=5 outstanding (the 5 newer stores)
        if (nx < nfull) { asm volatile("s_waitcnt vmcnt(5)" ::: "memory"); }
    }

    // ---- generic tail (rows beyond full tiles): scalar, barrier-free.
    // Not hit at bench shape (4,194,304 rows = 32768 x 128 exactly).
    if (blockIdx.x == 0 && wid == 0) {
        for (long long r = nfull * ROWS_PER_TILE + lane; r < n_rows; r += 64) {
            const float* gi = x   + r * NQ;
            float*       go = out + r * NQ;
            float pr = 1.0f;
            #pragma unroll
            for (int j = 0; j < NQ; ++j) { pr *= __cosf(gi[j]) * cw[j]; go[j] = pr; }
        }
    }
#undef STAGE
}

extern "C" void kernel_launch(void* const* d_in, const int* in_sizes, int n_in,
                              void* d_out, int out_size, void* d_ws, size_t ws_size,
                              hipStream_t stream) {
    const float* x = (const float*)d_in[0];
    const float* w = (const float*)d_in[1];
    float* out = (float*)d_out;

    const long long n_elem = in_sizes[0];
    const long long n_rows = n_elem / NQ;
    const long long total_u4 = (n_rows * NQ) / 4;
    const long long nfull = total_u4 / WQ;                 // full 128-row wave-tiles
    long long blocks = (nfull + WAVES - 1) / WAVES;
    if (blocks > MAX_BLOCKS) blocks = MAX_BLOCKS;
    if (blocks < 1) blocks = 1;                            // tail-only degenerate case

    hipLaunchKernelGGL(qcircuit_kernel, dim3((int)blocks), dim3(BLOCK), 0, stream,
                       x, w, out, n_rows, nfull);
}